// Round 4
// baseline (230.233 us; speedup 1.0000x reference)
//
#include <hip/hip_runtime.h>
#include <hip/hip_bf16.h>

#define N_NODES 10000
#define N_EDGES 100000

typedef __attribute__((ext_vector_type(8))) short short8;
typedef __attribute__((ext_vector_type(4))) short shortx4;
typedef __attribute__((ext_vector_type(4))) float f32x4;

static __device__ inline short bf16bits(float x) {
    union { __bf16 b; short s; } u;
    u.b = (__bf16)x;
    return u.s;
}
static __device__ inline unsigned short bf16u(float x) {
    union { __bf16 b; unsigned short s; } u;
    u.b = (__bf16)x;
    return u.s;
}
static __device__ inline float bf2f(unsigned short us) {
    union { unsigned int u; float f; } c;
    c.u = ((unsigned int)us) << 16;
    return c.f;
}
static __device__ inline short8 cvt8(const float* f) {
    short8 r;
#pragma unroll
    for (int j = 0; j < 8; ++j) r[j] = bf16bits(f[j]);
    return r;
}

// ---------------------------------------------------------------------------
// Precompute (unchanged from R3):
//  [0,32768):      fold L1s/L1v into Wgen -> Wc (bf16, MFMA B-frag order)
//  [32768,65536):  fold L2s/L2v into WS0/WS1 -> WB0/WB1 (bf16 B-frag, K=512)
//  [65536,165536): histogram edge receivers into deg
// ---------------------------------------------------------------------------
__global__ __launch_bounds__(256) void prep_kernel(
    const float* __restrict__ Wgen, const float* __restrict__ L1s,
    const float* __restrict__ L1v, const float* __restrict__ WS0,
    const float* __restrict__ WS1, const float* __restrict__ L2s,
    const float* __restrict__ L2v, const int* __restrict__ edge_index,
    unsigned short* __restrict__ Wc, unsigned short* __restrict__ WB0,
    unsigned short* __restrict__ WB1, int* __restrict__ deg) {
    const float S = 1.0f / 128.0f;
    int tid = blockIdx.x * 256 + threadIdx.x;
    if (tid < 32768) {
        int j = tid & 7;
        int lane = (tid >> 3) & 63;
        int ks = (tid >> 9) & 7;
        int nt = tid >> 12;
        int col = nt * 16 + (lane & 15);
        int u = (lane >> 4) * 8 + j;
        int r = ks;
        int p, c2;
        const float* M;
        float sc = S;
        if (col < 32)      { p = 0; M = L1s; c2 = col; }
        else if (col < 64) { p = 1; M = L1v; c2 = col - 32; }
        else if (col < 96) { p = 2; M = L1v; c2 = col - 64; }
        else               { p = 3; M = L1s; c2 = col - 96; sc = S * 0.57735026918962576f; }
        const float* wg = Wgen + r * 4096 + p * 1024 + u * 32;
        float acc = 0.f;
#pragma unroll
        for (int w = 0; w < 32; ++w) acc += wg[w] * M[w * 32 + c2];
        Wc[tid] = bf16u(acc * sc);
    } else if (tid < 65536) {
        int idx = tid - 32768;
        int table = idx >> 14;
        int r14 = idx & 16383;
        int j = r14 & 7;
        int lane = (r14 >> 3) & 63;
        int ks = (r14 >> 9) & 15;
        int k = ks * 32 + (lane >> 4) * 8 + j;
        int u = k >> 4, v = k & 15;
        int w = ((r14 >> 13) & 1) * 16 + (lane & 15);
        const float* WS = table ? WS1 : WS0;
        const float* L2 = table ? L2v : L2s;
        const float* src = WS + u * 512 + v * 32;
        float acc = 0.f;
#pragma unroll
        for (int x = 0; x < 32; ++x) acc += src[x] * L2[x * 32 + w];
        unsigned short val = bf16u(acc * S);
        if (table) WB1[r14] = val; else WB0[r14] = val;
    } else if (tid < 65536 + N_EDGES) {
        int e = tid - 65536;
        atomicAdd(&deg[edge_index[N_EDGES + e]], 1);
    }
}

__global__ __launch_bounds__(256) void scan_kernel(
    const int* __restrict__ deg, int* __restrict__ off, int* __restrict__ cursor) {
    __shared__ int part[256];
    int t = threadIdx.x;
    int base = t * 40;
    int s = 0;
    for (int i = 0; i < 40; ++i) {
        int idx = base + i;
        if (idx < N_NODES) s += deg[idx];
    }
    part[t] = s;
    __syncthreads();
    for (int d = 1; d < 256; d <<= 1) {
        int v = (t >= d) ? part[t - d] : 0;
        __syncthreads();
        part[t] += v;
        __syncthreads();
    }
    int run = part[t] - s;
    for (int i = 0; i < 40; ++i) {
        int idx = base + i;
        if (idx < N_NODES) {
            off[idx] = run;
            cursor[idx] = run;
            run += deg[idx];
        }
    }
    if (t == 255) off[N_NODES] = run;
}

__global__ __launch_bounds__(256) void slot_kernel(
    const int* __restrict__ edge_index, int* __restrict__ cursor,
    int* __restrict__ slot) {
    int e = blockIdx.x * 256 + threadIdx.x;
    if (e < N_EDGES) {
        int r = edge_index[N_EDGES + e];
        slot[e] = atomicAdd(&cursor[r], 1);
    }
}

// ---------------------------------------------------------------------------
// Edge kernel v2: software-pipelined tile loop.
//  - stage1 prefetch (2 tiles ahead): sender index
//  - stage2 prefetch (1 tile ahead): node_feats row, edge_feats, own edge_attrs
//  - epilogue without shfl: per-lane loads of edge_attrs/slot for its 4 D rows
//  - Msg layout channel-interleaved: Msg[slot*128 + c*4 + comp] -> short4 stores
// ---------------------------------------------------------------------------
__global__ __launch_bounds__(256, 2) void edge_kernel(
    const float* __restrict__ node_feats, const float* __restrict__ edge_attrs,
    const float* __restrict__ edge_feats, const int* __restrict__ edge_index,
    const unsigned short* __restrict__ Wc, const int* __restrict__ slot,
    unsigned short* __restrict__ Msg) {
    __shared__ f32x4 sWv[4096];  // 64KB bf16 weights in B-fragment order
    {
        const f32x4* src = (const f32x4*)Wc;
        for (int i = threadIdx.x; i < 4096; i += 256) sWv[i] = src[i];
    }
    __syncthreads();
    const short8* sW8 = (const short8*)sWv;

    const int lane = threadIdx.x & 63;
    const int m = lane & 15, q = lane >> 4;
    const int wave = (blockIdx.x * 256 + threadIdx.x) >> 6;
    const int stride = gridDim.x * 4;
    const int NT = N_EDGES / 16;

    int tile = wave;
    if (tile >= NT) return;

    float xsC[8], xvC[24], efC[8];
    f32x4 eaC;
    float xsN[8], xvN[24], efN[8];
    f32x4 eaN;

    // ---- prologue: stage1 for t0 and t0+stride, stage2 for t0
    int sndC = edge_index[tile * 16 + m];
    int sndN;
    {
        int tn = tile + stride;
        sndN = (tn < NT) ? edge_index[tn * 16 + m] : sndC;
    }
    {
        const float* g = node_feats + sndC * 128;
        *(f32x4*)&xsC[0] = *(const f32x4*)(g + q * 8);
        *(f32x4*)&xsC[4] = *(const f32x4*)(g + q * 8 + 4);
#pragma unroll
        for (int i = 0; i < 6; ++i)
            *(f32x4*)&xvC[i * 4] = *(const f32x4*)(g + 32 + q * 24 + i * 4);
        int e = tile * 16 + m;
        *(f32x4*)&efC[0] = *(const f32x4*)(edge_feats + e * 8);
        *(f32x4*)&efC[4] = *(const f32x4*)(edge_feats + e * 8 + 4);
        eaC = *(const f32x4*)(edge_attrs + e * 4);
    }

    while (tile < NT) {
        const int tn = tile + stride;
        // ---- stage1 prefetch: sender for tile+2*stride
        int snd2;
        {
            int t2 = tile + 2 * stride;
            snd2 = (t2 < NT) ? edge_index[t2 * 16 + m] : sndN;
        }
        // ---- stage2 prefetch for tn (uses sndN, loaded one full iter ago)
        if (tn < NT) {
            const float* g = node_feats + sndN * 128;
            *(f32x4*)&xsN[0] = *(const f32x4*)(g + q * 8);
            *(f32x4*)&xsN[4] = *(const f32x4*)(g + q * 8 + 4);
#pragma unroll
            for (int i = 0; i < 6; ++i)
                *(f32x4*)&xvN[i * 4] = *(const f32x4*)(g + 32 + q * 24 + i * 4);
            int en = tn * 16 + m;
            *(f32x4*)&efN[0] = *(const f32x4*)(edge_feats + en * 8);
            *(f32x4*)&efN[4] = *(const f32x4*)(edge_feats + en * 8 + 4);
            eaN = *(const f32x4*)(edge_attrs + en * 4);
        }
        // ---- epilogue helper loads for current tile (hidden behind MFMAs)
        f32x4 eaR[4];
        int slR[4];
#pragma unroll
        for (int t = 0; t < 4; ++t) {
            int er = tile * 16 + q * 4 + t;
            eaR[t] = *(const f32x4*)(edge_attrs + er * 4);
            slR[t] = slot[er];
        }

        // ---- compute current tile
        float ys = eaC.x, yv0 = eaC.y, yv1 = eaC.z, yv2 = eaC.w;
        float dt[8];
#pragma unroll
        for (int j = 0; j < 8; ++j)
            dt[j] = xvC[j * 3] * yv0 + xvC[j * 3 + 1] * yv1 + xvC[j * 3 + 2] * yv2;

        f32x4 z = {0.f, 0.f, 0.f, 0.f};
        f32x4 fA[2] = {z, z}, fB[2] = {z, z}, fD[2] = {z, z};
        f32x4 fC[3][2] = {{z, z}, {z, z}, {z, z}};

#pragma unroll
        for (int ks = 0; ks < 8; ++ks) {
            float h = efC[ks];
            float t0[8], t1[8], t2[8], t3[8], t4[8];
#pragma unroll
            for (int j = 0; j < 8; ++j) {
                t0[j] = h * xsC[j];
                t1[j] = h * xvC[j * 3 + 0];
                t2[j] = h * xvC[j * 3 + 1];
                t3[j] = h * xvC[j * 3 + 2];
                t4[j] = h * dt[j];
            }
            short8 a_xs = cvt8(t0);
            short8 a_v0 = cvt8(t1);
            short8 a_v1 = cvt8(t2);
            short8 a_v2 = cvt8(t3);
            short8 a_d  = cvt8(t4);
#define BFRAG(nt) sW8[((nt) * 8 + ks) * 64 + lane]
            fA[0] = __builtin_amdgcn_mfma_f32_16x16x32_bf16(a_xs, BFRAG(0), fA[0], 0, 0, 0);
            fA[1] = __builtin_amdgcn_mfma_f32_16x16x32_bf16(a_xs, BFRAG(1), fA[1], 0, 0, 0);
            fB[0] = __builtin_amdgcn_mfma_f32_16x16x32_bf16(a_xs, BFRAG(2), fB[0], 0, 0, 0);
            fB[1] = __builtin_amdgcn_mfma_f32_16x16x32_bf16(a_xs, BFRAG(3), fB[1], 0, 0, 0);
            short8 bc0 = BFRAG(4), bc1 = BFRAG(5);
            fC[0][0] = __builtin_amdgcn_mfma_f32_16x16x32_bf16(a_v0, bc0, fC[0][0], 0, 0, 0);
            fC[0][1] = __builtin_amdgcn_mfma_f32_16x16x32_bf16(a_v0, bc1, fC[0][1], 0, 0, 0);
            fC[1][0] = __builtin_amdgcn_mfma_f32_16x16x32_bf16(a_v1, bc0, fC[1][0], 0, 0, 0);
            fC[1][1] = __builtin_amdgcn_mfma_f32_16x16x32_bf16(a_v1, bc1, fC[1][1], 0, 0, 0);
            fC[2][0] = __builtin_amdgcn_mfma_f32_16x16x32_bf16(a_v2, bc0, fC[2][0], 0, 0, 0);
            fC[2][1] = __builtin_amdgcn_mfma_f32_16x16x32_bf16(a_v2, bc1, fC[2][1], 0, 0, 0);
            fD[0] = __builtin_amdgcn_mfma_f32_16x16x32_bf16(a_d, BFRAG(6), fD[0], 0, 0, 0);
            fD[1] = __builtin_amdgcn_mfma_f32_16x16x32_bf16(a_d, BFRAG(7), fD[1], 0, 0, 0);
#undef BFRAG
        }

        // ---- epilogue: lane owns rows q*4+t, col m and 16+m; short4 stores
#pragma unroll
        for (int t = 0; t < 4; ++t) {
            float ysr = eaR[t].x, y0r = eaR[t].y, y1r = eaR[t].z, y2r = eaR[t].w;
            int dr = slR[t];
#pragma unroll
            for (int nt = 0; nt < 2; ++nt) {
                int col = nt * 16 + m;
                float pb = fB[nt][t];
                shortx4 pk;
                pk[0] = bf16bits(ysr * fA[nt][t] + fD[nt][t]);
                pk[1] = bf16bits(y0r * pb + ysr * fC[0][nt][t]);
                pk[2] = bf16bits(y1r * pb + ysr * fC[1][nt][t]);
                pk[3] = bf16bits(y2r * pb + ysr * fC[2][nt][t]);
                *(shortx4*)(Msg + (size_t)dr * 128 + col * 4) = pk;
            }
        }

        // ---- rotate pipeline
        tile = tn;
#pragma unroll
        for (int j = 0; j < 8; ++j) { xsC[j] = xsN[j]; efC[j] = efN[j]; }
#pragma unroll
        for (int j = 0; j < 24; ++j) xvC[j] = xvN[j];
        eaC = eaN;
        sndN = snd2;
    }
}

// ---------------------------------------------------------------------------
// Fused gather + node kernel. Block = 16 nodes, 256 threads.
// Phase 1: gather CSR rows (16B loads, channel-interleaved layout) -> sM.
// Phase 2: wave p computes path p as 16x32x512 MFMA GEMM vs WB0/WB1.
// ---------------------------------------------------------------------------
__global__ __launch_bounds__(256) void node_kernel(
    const float* __restrict__ node_attrs, const unsigned short* __restrict__ Msg,
    const int* __restrict__ off, const unsigned short* __restrict__ WB0,
    const unsigned short* __restrict__ WB1, float* __restrict__ out) {
    __shared__ float sM[16][129];
    __shared__ float sAt[16][17];
    int n0 = blockIdx.x * 16;

    // Phase 1: 16 threads per node; thread owns channels cg*2, cg*2+1 (x4 comps)
    int nl = threadIdx.x >> 4;
    int cg = threadIdx.x & 15;
    int n = n0 + nl;
    int s0 = off[n], s1 = off[n + 1];
    float acc[8];
#pragma unroll
    for (int j = 0; j < 8; ++j) acc[j] = 0.f;
    for (int s = s0; s < s1; ++s) {
        f32x4 raw = *(const f32x4*)(Msg + (size_t)s * 128 + cg * 8);
        const unsigned short* us = (const unsigned short*)&raw;
#pragma unroll
        for (int j = 0; j < 8; ++j) acc[j] += bf2f(us[j]);
    }
#pragma unroll
    for (int j = 0; j < 8; ++j)
        sM[nl][(j & 3) * 32 + cg * 2 + (j >> 2)] = acc[j];
    sAt[nl][cg] = node_attrs[n * 16 + cg];
    __syncthreads();

    // Phase 2
    int p = threadIdx.x >> 6;
    int lane = threadIdx.x & 63;
    int m = lane & 15, q = lane >> 4;
    const unsigned short* WB = (p == 0) ? WB0 : WB1;
    int chb = p * 32;
    f32x4 z = {0.f, 0.f, 0.f, 0.f};
    f32x4 D0 = z, D1 = z;
#pragma unroll
    for (int ks = 0; ks < 16; ++ks) {
        int kb = ks * 32 + q * 8;
        float t[8];
#pragma unroll
        for (int j = 0; j < 8; ++j) {
            int k = kb + j;
            t[j] = sM[m][chb + (k >> 4)] * sAt[m][k & 15];
        }
        short8 a = cvt8(t);
        short8 b0 = *(const short8*)(WB + (ks * 64 + lane) * 8);
        short8 b1 = *(const short8*)(WB + ((16 + ks) * 64 + lane) * 8);
        D0 = __builtin_amdgcn_mfma_f32_16x16x32_bf16(a, b0, D0, 0, 0, 0);
        D1 = __builtin_amdgcn_mfma_f32_16x16x32_bf16(a, b1, D1, 0, 0, 0);
    }

    // Epilogue
#pragma unroll
    for (int t4 = 0; t4 < 4; ++t4) {
        int nl2 = q * 4 + t4;
        int nn = n0 + nl2;
        if (p == 0) {
            out[nn * 128 + m]      = sM[nl2][m] + D0[t4];
            out[nn * 128 + 16 + m] = sM[nl2][16 + m] + D1[t4];
        } else {
            int i = p - 1;
            out[nn * 128 + 32 + m * 3 + i]        = sM[nl2][chb + m] + D0[t4];
            out[nn * 128 + 32 + (16 + m) * 3 + i] = sM[nl2][chb + 16 + m] + D1[t4];
        }
    }
}

extern "C" void kernel_launch(void* const* d_in, const int* in_sizes, int n_in,
                              void* d_out, int out_size, void* d_ws, size_t ws_size,
                              hipStream_t stream) {
    (void)in_sizes; (void)n_in; (void)out_size; (void)ws_size;
    const float* node_attrs = (const float*)d_in[0];
    const float* node_feats = (const float*)d_in[1];
    const float* edge_attrs = (const float*)d_in[2];
    const float* edge_feats = (const float*)d_in[3];
    const int*   edge_index = (const int*)d_in[4];
    const float* Wgen = (const float*)d_in[5];
    const float* L1s  = (const float*)d_in[6];
    const float* L1v  = (const float*)d_in[7];
    const float* WS0  = (const float*)d_in[8];
    const float* WS1  = (const float*)d_in[9];
    const float* L2s  = (const float*)d_in[10];
    const float* L2v  = (const float*)d_in[11];
    float* out = (float*)d_out;
    char* ws = (char*)d_ws;

    unsigned short* Msg = (unsigned short*)ws;                 // 25,600,000
    unsigned short* Wc  = (unsigned short*)(ws + 25600000);    //     65,536
    unsigned short* WB0 = (unsigned short*)(ws + 25665536);    //     32,768
    unsigned short* WB1 = (unsigned short*)(ws + 25698304);    //     32,768
    int* deg    = (int*)(ws + 25731072);                       //     40,000
    int* off    = (int*)(ws + 25771072);                       //     40,004
    int* cursor = (int*)(ws + 25811080);                       //     40,000
    int* slot   = (int*)(ws + 25851080);                       //    400,000

    hipMemsetAsync(deg, 0, 40000, stream);
    prep_kernel<<<647, 256, 0, stream>>>(Wgen, L1s, L1v, WS0, WS1, L2s, L2v,
                                         edge_index, Wc, WB0, WB1, deg);
    scan_kernel<<<1, 256, 0, stream>>>(deg, off, cursor);
    slot_kernel<<<391, 256, 0, stream>>>(edge_index, cursor, slot);
    edge_kernel<<<512, 256, 0, stream>>>(node_feats, edge_attrs, edge_feats,
                                         edge_index, Wc, slot, Msg);
    node_kernel<<<625, 256, 0, stream>>>(node_attrs, Msg, off, WB0, WB1, out);
}

// Round 5
// 197.226 us; speedup vs baseline: 1.1674x; 1.1674x over previous
//
#include <hip/hip_runtime.h>
#include <hip/hip_bf16.h>

#define N_NODES 10000
#define N_EDGES 100000

typedef __attribute__((ext_vector_type(8))) short short8;
typedef __attribute__((ext_vector_type(4))) short shortx4;
typedef __attribute__((ext_vector_type(4))) float f32x4;

static __device__ inline short bf16bits(float x) {
    union { __bf16 b; short s; } u;
    u.b = (__bf16)x;
    return u.s;
}
static __device__ inline unsigned short bf16u(float x) {
    union { __bf16 b; unsigned short s; } u;
    u.b = (__bf16)x;
    return u.s;
}
static __device__ inline float bf2f(unsigned short us) {
    union { unsigned int u; float f; } c;
    c.u = ((unsigned int)us) << 16;
    return c.f;
}
static __device__ inline short8 cvt8(const float* f) {
    short8 r;
#pragma unroll
    for (int j = 0; j < 8; ++j) r[j] = bf16bits(f[j]);
    return r;
}

// ---------------------------------------------------------------------------
// Precompute (unchanged from R3):
//  [0,32768):      fold L1s/L1v into Wgen -> Wc (bf16, MFMA B-frag order)
//  [32768,65536):  fold L2s/L2v into WS0/WS1 -> WB0/WB1 (bf16 B-frag, K=512)
//  [65536,165536): histogram edge receivers into deg
// ---------------------------------------------------------------------------
__global__ __launch_bounds__(256) void prep_kernel(
    const float* __restrict__ Wgen, const float* __restrict__ L1s,
    const float* __restrict__ L1v, const float* __restrict__ WS0,
    const float* __restrict__ WS1, const float* __restrict__ L2s,
    const float* __restrict__ L2v, const int* __restrict__ edge_index,
    unsigned short* __restrict__ Wc, unsigned short* __restrict__ WB0,
    unsigned short* __restrict__ WB1, int* __restrict__ deg) {
    const float S = 1.0f / 128.0f;
    int tid = blockIdx.x * 256 + threadIdx.x;
    if (tid < 32768) {
        int j = tid & 7;
        int lane = (tid >> 3) & 63;
        int ks = (tid >> 9) & 7;
        int nt = tid >> 12;
        int col = nt * 16 + (lane & 15);
        int u = (lane >> 4) * 8 + j;
        int r = ks;
        int p, c2;
        const float* M;
        float sc = S;
        if (col < 32)      { p = 0; M = L1s; c2 = col; }
        else if (col < 64) { p = 1; M = L1v; c2 = col - 32; }
        else if (col < 96) { p = 2; M = L1v; c2 = col - 64; }
        else               { p = 3; M = L1s; c2 = col - 96; sc = S * 0.57735026918962576f; }
        const float* wg = Wgen + r * 4096 + p * 1024 + u * 32;
        float acc = 0.f;
#pragma unroll
        for (int w = 0; w < 32; ++w) acc += wg[w] * M[w * 32 + c2];
        Wc[tid] = bf16u(acc * sc);
    } else if (tid < 65536) {
        int idx = tid - 32768;
        int table = idx >> 14;
        int r14 = idx & 16383;
        int j = r14 & 7;
        int lane = (r14 >> 3) & 63;
        int ks = (r14 >> 9) & 15;
        int k = ks * 32 + (lane >> 4) * 8 + j;
        int u = k >> 4, v = k & 15;
        int w = ((r14 >> 13) & 1) * 16 + (lane & 15);
        const float* WS = table ? WS1 : WS0;
        const float* L2 = table ? L2v : L2s;
        const float* src = WS + u * 512 + v * 32;
        float acc = 0.f;
#pragma unroll
        for (int x = 0; x < 32; ++x) acc += src[x] * L2[x * 32 + w];
        unsigned short val = bf16u(acc * S);
        if (table) WB1[r14] = val; else WB0[r14] = val;
    } else if (tid < 65536 + N_EDGES) {
        int e = tid - 65536;
        atomicAdd(&deg[edge_index[N_EDGES + e]], 1);
    }
}

__global__ __launch_bounds__(256) void scan_kernel(
    const int* __restrict__ deg, int* __restrict__ off, int* __restrict__ cursor) {
    __shared__ int part[256];
    int t = threadIdx.x;
    int base = t * 40;
    int s = 0;
    for (int i = 0; i < 40; ++i) {
        int idx = base + i;
        if (idx < N_NODES) s += deg[idx];
    }
    part[t] = s;
    __syncthreads();
    for (int d = 1; d < 256; d <<= 1) {
        int v = (t >= d) ? part[t - d] : 0;
        __syncthreads();
        part[t] += v;
        __syncthreads();
    }
    int run = part[t] - s;
    for (int i = 0; i < 40; ++i) {
        int idx = base + i;
        if (idx < N_NODES) {
            off[idx] = run;
            cursor[idx] = run;
            run += deg[idx];
        }
    }
    if (t == 255) off[N_NODES] = run;
}

__global__ __launch_bounds__(256) void slot_kernel(
    const int* __restrict__ edge_index, int* __restrict__ cursor,
    int* __restrict__ slot) {
    int e = blockIdx.x * 256 + threadIdx.x;
    if (e < N_EDGES) {
        int r = edge_index[N_EDGES + e];
        slot[e] = atomicAdd(&cursor[r], 1);
    }
}

// ---------------------------------------------------------------------------
// Edge kernel v3: nt-split for occupancy.
// blockIdx.y = h in {0,1}: this block computes output columns h*16..h*16+15 of
// each path, staging only tables {h, 2+h, 4+h, 6+h} (32 KB LDS, was 64 KB).
// Per 16-edge tile per wave: 48 MFMAs (6 per ks). Shfl-free epilogue with
// interleaved short4 Msg stores: Msg[slot*128 + col*4 + comp].
// No launch_bounds min-waves (R4 lesson: forcing the cap -> spills).
// ---------------------------------------------------------------------------
__global__ __launch_bounds__(256) void edge_kernel(
    const float* __restrict__ node_feats, const float* __restrict__ edge_attrs,
    const float* __restrict__ edge_feats, const int* __restrict__ edge_index,
    const unsigned short* __restrict__ Wc, const int* __restrict__ slot,
    unsigned short* __restrict__ Msg) {
    __shared__ short8 sW8[2048];  // 32 KB: 4 tables x (8 ks x 64 lanes)
    const int h = blockIdx.y;
    {
        for (int i = threadIdx.x; i < 2048; i += 256) {
            int tt = i >> 9;            // local table 0..3 (A,B,C,D)
            int rest = i & 511;         // ks*64 + lane
            int t = tt * 2 + h;         // global table
            sW8[i] = *(const short8*)(Wc + ((t * 512 + rest) << 3));
        }
    }
    __syncthreads();

    const int lane = threadIdx.x & 63;
    const int m = lane & 15, q = lane >> 4;
    const int wave = (blockIdx.x * 256 + threadIdx.x) >> 6;
    const int stride = gridDim.x * 4;
    const int NT = N_EDGES / 16;
    const int colbase = h * 16;

    for (int tile = wave; tile < NT; tile += stride) {
        int e = tile * 16 + m;
        int snd = edge_index[e];
        const float* g = node_feats + snd * 128;

        float xs[8], xv[24], ef[8], dt[8];
        *(f32x4*)&xs[0] = *(const f32x4*)(g + q * 8);
        *(f32x4*)&xs[4] = *(const f32x4*)(g + q * 8 + 4);
#pragma unroll
        for (int i = 0; i < 6; ++i)
            *(f32x4*)&xv[i * 4] = *(const f32x4*)(g + 32 + q * 24 + i * 4);
        *(f32x4*)&ef[0] = *(const f32x4*)(edge_feats + e * 8);
        *(f32x4*)&ef[4] = *(const f32x4*)(edge_feats + e * 8 + 4);
        f32x4 eaC = *(const f32x4*)(edge_attrs + e * 4);

        // epilogue helper loads (issued early, hidden behind MFMAs)
        f32x4 eaR[4];
        int slR[4];
#pragma unroll
        for (int t = 0; t < 4; ++t) {
            int er = tile * 16 + q * 4 + t;
            eaR[t] = *(const f32x4*)(edge_attrs + er * 4);
            slR[t] = slot[er];
        }

        float yv0 = eaC.y, yv1 = eaC.z, yv2 = eaC.w;
#pragma unroll
        for (int j = 0; j < 8; ++j)
            dt[j] = xv[j * 3] * yv0 + xv[j * 3 + 1] * yv1 + xv[j * 3 + 2] * yv2;

        f32x4 z = {0.f, 0.f, 0.f, 0.f};
        f32x4 fA = z, fB = z, fD = z;
        f32x4 fC0 = z, fC1 = z, fC2 = z;

#pragma unroll
        for (int ks = 0; ks < 8; ++ks) {
            float hh = ef[ks];
            float t0[8], t1[8], t2[8], t3[8], t4[8];
#pragma unroll
            for (int j = 0; j < 8; ++j) {
                t0[j] = hh * xs[j];
                t1[j] = hh * xv[j * 3 + 0];
                t2[j] = hh * xv[j * 3 + 1];
                t3[j] = hh * xv[j * 3 + 2];
                t4[j] = hh * dt[j];
            }
            short8 a_xs = cvt8(t0);
            short8 a_v0 = cvt8(t1);
            short8 a_v1 = cvt8(t2);
            short8 a_v2 = cvt8(t3);
            short8 a_d  = cvt8(t4);
            short8 bA = sW8[(0 * 8 + ks) * 64 + lane];
            short8 bB = sW8[(1 * 8 + ks) * 64 + lane];
            short8 bC = sW8[(2 * 8 + ks) * 64 + lane];
            short8 bD = sW8[(3 * 8 + ks) * 64 + lane];
            fA  = __builtin_amdgcn_mfma_f32_16x16x32_bf16(a_xs, bA, fA, 0, 0, 0);
            fB  = __builtin_amdgcn_mfma_f32_16x16x32_bf16(a_xs, bB, fB, 0, 0, 0);
            fC0 = __builtin_amdgcn_mfma_f32_16x16x32_bf16(a_v0, bC, fC0, 0, 0, 0);
            fC1 = __builtin_amdgcn_mfma_f32_16x16x32_bf16(a_v1, bC, fC1, 0, 0, 0);
            fC2 = __builtin_amdgcn_mfma_f32_16x16x32_bf16(a_v2, bC, fC2, 0, 0, 0);
            fD  = __builtin_amdgcn_mfma_f32_16x16x32_bf16(a_d,  bD, fD, 0, 0, 0);
        }

        // epilogue: lane owns D-frag rows q*4+t, col = colbase + m
#pragma unroll
        for (int t = 0; t < 4; ++t) {
            float ysr = eaR[t].x, y0r = eaR[t].y, y1r = eaR[t].z, y2r = eaR[t].w;
            int dr = slR[t];
            float pb = fB[t];
            shortx4 pk;
            pk[0] = bf16bits(ysr * fA[t] + fD[t]);
            pk[1] = bf16bits(y0r * pb + ysr * fC0[t]);
            pk[2] = bf16bits(y1r * pb + ysr * fC1[t]);
            pk[3] = bf16bits(y2r * pb + ysr * fC2[t]);
            *(shortx4*)(Msg + (size_t)dr * 128 + (colbase + m) * 4) = pk;
        }
    }
}

// ---------------------------------------------------------------------------
// Fused gather + node kernel (R4 form, matches interleaved Msg layout).
// Block = 16 nodes. Phase 1: CSR gather (16B loads) -> sM[comp*32+col].
// Phase 2: wave p computes path p as 16x32x512 MFMA GEMM vs WB0/WB1.
// ---------------------------------------------------------------------------
__global__ __launch_bounds__(256) void node_kernel(
    const float* __restrict__ node_attrs, const unsigned short* __restrict__ Msg,
    const int* __restrict__ off, const unsigned short* __restrict__ WB0,
    const unsigned short* __restrict__ WB1, float* __restrict__ out) {
    __shared__ float sM[16][129];
    __shared__ float sAt[16][17];
    int n0 = blockIdx.x * 16;

    int nl = threadIdx.x >> 4;
    int cg = threadIdx.x & 15;
    int n = n0 + nl;
    int s0 = off[n], s1 = off[n + 1];
    float acc[8];
#pragma unroll
    for (int j = 0; j < 8; ++j) acc[j] = 0.f;
    for (int s = s0; s < s1; ++s) {
        f32x4 raw = *(const f32x4*)(Msg + (size_t)s * 128 + cg * 8);
        const unsigned short* us = (const unsigned short*)&raw;
#pragma unroll
        for (int j = 0; j < 8; ++j) acc[j] += bf2f(us[j]);
    }
#pragma unroll
    for (int j = 0; j < 8; ++j)
        sM[nl][(j & 3) * 32 + cg * 2 + (j >> 2)] = acc[j];
    sAt[nl][cg] = node_attrs[n * 16 + cg];
    __syncthreads();

    int p = threadIdx.x >> 6;
    int lane = threadIdx.x & 63;
    int m = lane & 15, q = lane >> 4;
    const unsigned short* WB = (p == 0) ? WB0 : WB1;
    int chb = p * 32;
    f32x4 z = {0.f, 0.f, 0.f, 0.f};
    f32x4 D0 = z, D1 = z;
#pragma unroll
    for (int ks = 0; ks < 16; ++ks) {
        int kb = ks * 32 + q * 8;
        float t[8];
#pragma unroll
        for (int j = 0; j < 8; ++j) {
            int k = kb + j;
            t[j] = sM[m][chb + (k >> 4)] * sAt[m][k & 15];
        }
        short8 a = cvt8(t);
        short8 b0 = *(const short8*)(WB + (ks * 64 + lane) * 8);
        short8 b1 = *(const short8*)(WB + ((16 + ks) * 64 + lane) * 8);
        D0 = __builtin_amdgcn_mfma_f32_16x16x32_bf16(a, b0, D0, 0, 0, 0);
        D1 = __builtin_amdgcn_mfma_f32_16x16x32_bf16(a, b1, D1, 0, 0, 0);
    }

#pragma unroll
    for (int t4 = 0; t4 < 4; ++t4) {
        int nl2 = q * 4 + t4;
        int nn = n0 + nl2;
        if (p == 0) {
            out[nn * 128 + m]      = sM[nl2][m] + D0[t4];
            out[nn * 128 + 16 + m] = sM[nl2][16 + m] + D1[t4];
        } else {
            int i = p - 1;
            out[nn * 128 + 32 + m * 3 + i]        = sM[nl2][chb + m] + D0[t4];
            out[nn * 128 + 32 + (16 + m) * 3 + i] = sM[nl2][chb + 16 + m] + D1[t4];
        }
    }
}

extern "C" void kernel_launch(void* const* d_in, const int* in_sizes, int n_in,
                              void* d_out, int out_size, void* d_ws, size_t ws_size,
                              hipStream_t stream) {
    (void)in_sizes; (void)n_in; (void)out_size; (void)ws_size;
    const float* node_attrs = (const float*)d_in[0];
    const float* node_feats = (const float*)d_in[1];
    const float* edge_attrs = (const float*)d_in[2];
    const float* edge_feats = (const float*)d_in[3];
    const int*   edge_index = (const int*)d_in[4];
    const float* Wgen = (const float*)d_in[5];
    const float* L1s  = (const float*)d_in[6];
    const float* L1v  = (const float*)d_in[7];
    const float* WS0  = (const float*)d_in[8];
    const float* WS1  = (const float*)d_in[9];
    const float* L2s  = (const float*)d_in[10];
    const float* L2v  = (const float*)d_in[11];
    float* out = (float*)d_out;
    char* ws = (char*)d_ws;

    unsigned short* Msg = (unsigned short*)ws;                 // 25,600,000
    unsigned short* Wc  = (unsigned short*)(ws + 25600000);    //     65,536
    unsigned short* WB0 = (unsigned short*)(ws + 25665536);    //     32,768
    unsigned short* WB1 = (unsigned short*)(ws + 25698304);    //     32,768
    int* deg    = (int*)(ws + 25731072);                       //     40,000
    int* off    = (int*)(ws + 25771072);                       //     40,004
    int* cursor = (int*)(ws + 25811080);                       //     40,000
    int* slot   = (int*)(ws + 25851080);                       //    400,000

    hipMemsetAsync(deg, 0, 40000, stream);
    prep_kernel<<<647, 256, 0, stream>>>(Wgen, L1s, L1v, WS0, WS1, L2s, L2v,
                                         edge_index, Wc, WB0, WB1, deg);
    scan_kernel<<<1, 256, 0, stream>>>(deg, off, cursor);
    slot_kernel<<<391, 256, 0, stream>>>(edge_index, cursor, slot);
    edge_kernel<<<dim3(512, 2), 256, 0, stream>>>(node_feats, edge_attrs,
                                                  edge_feats, edge_index, Wc,
                                                  slot, Msg);
    node_kernel<<<625, 256, 0, stream>>>(node_attrs, Msg, off, WB0, WB1, out);
}

// Round 6
// 161.186 us; speedup vs baseline: 1.4284x; 1.2236x over previous
//
#include <hip/hip_runtime.h>
#include <hip/hip_bf16.h>

#define N_NODES 10000
#define N_EDGES 100000

typedef __attribute__((ext_vector_type(8))) short short8;
typedef __attribute__((ext_vector_type(4))) short shortx4;
typedef __attribute__((ext_vector_type(4))) float f32x4;

static __device__ inline short bf16bits(float x) {
    union { __bf16 b; short s; } u;
    u.b = (__bf16)x;
    return u.s;
}
static __device__ inline unsigned short bf16u(float x) {
    union { __bf16 b; unsigned short s; } u;
    u.b = (__bf16)x;
    return u.s;
}
static __device__ inline float bf2f(unsigned short us) {
    union { unsigned int u; float f; } c;
    c.u = ((unsigned int)us) << 16;
    return c.f;
}
static __device__ inline short8 cvt8(const float* f) {
    short8 r;
#pragma unroll
    for (int j = 0; j < 8; ++j) r[j] = bf16bits(f[j]);
    return r;
}

// ---------------------------------------------------------------------------
// Precompute (unchanged):
//  [0,32768):      fold L1s/L1v into Wgen -> Wc (bf16, MFMA B-frag order)
//  [32768,65536):  fold L2s/L2v into WS0/WS1 -> WB0/WB1 (bf16 B-frag, K=512)
//  [65536,165536): histogram edge receivers into deg
// ---------------------------------------------------------------------------
__global__ __launch_bounds__(256) void prep_kernel(
    const float* __restrict__ Wgen, const float* __restrict__ L1s,
    const float* __restrict__ L1v, const float* __restrict__ WS0,
    const float* __restrict__ WS1, const float* __restrict__ L2s,
    const float* __restrict__ L2v, const int* __restrict__ edge_index,
    unsigned short* __restrict__ Wc, unsigned short* __restrict__ WB0,
    unsigned short* __restrict__ WB1, int* __restrict__ deg) {
    const float S = 1.0f / 128.0f;
    int tid = blockIdx.x * 256 + threadIdx.x;
    if (tid < 32768) {
        int j = tid & 7;
        int lane = (tid >> 3) & 63;
        int ks = (tid >> 9) & 7;
        int nt = tid >> 12;
        int col = nt * 16 + (lane & 15);
        int u = (lane >> 4) * 8 + j;
        int r = ks;
        int p, c2;
        const float* M;
        float sc = S;
        if (col < 32)      { p = 0; M = L1s; c2 = col; }
        else if (col < 64) { p = 1; M = L1v; c2 = col - 32; }
        else if (col < 96) { p = 2; M = L1v; c2 = col - 64; }
        else               { p = 3; M = L1s; c2 = col - 96; sc = S * 0.57735026918962576f; }
        const float* wg = Wgen + r * 4096 + p * 1024 + u * 32;
        float acc = 0.f;
#pragma unroll
        for (int w = 0; w < 32; ++w) acc += wg[w] * M[w * 32 + c2];
        Wc[tid] = bf16u(acc * sc);
    } else if (tid < 65536) {
        int idx = tid - 32768;
        int table = idx >> 14;
        int r14 = idx & 16383;
        int j = r14 & 7;
        int lane = (r14 >> 3) & 63;
        int ks = (r14 >> 9) & 15;
        int k = ks * 32 + (lane >> 4) * 8 + j;
        int u = k >> 4, v = k & 15;
        int w = ((r14 >> 13) & 1) * 16 + (lane & 15);
        const float* WS = table ? WS1 : WS0;
        const float* L2 = table ? L2v : L2s;
        const float* src = WS + u * 512 + v * 32;
        float acc = 0.f;
#pragma unroll
        for (int x = 0; x < 32; ++x) acc += src[x] * L2[x * 32 + w];
        unsigned short val = bf16u(acc * S);
        if (table) WB1[r14] = val; else WB0[r14] = val;
    } else if (tid < 65536 + N_EDGES) {
        int e = tid - 65536;
        atomicAdd(&deg[edge_index[N_EDGES + e]], 1);
    }
}

// Exclusive scan, 1024 threads x 10 elems.
__global__ __launch_bounds__(1024) void scan_kernel(
    const int* __restrict__ deg, int* __restrict__ off, int* __restrict__ cursor) {
    __shared__ int part[1024];
    int t = threadIdx.x;
    int base = t * 10;
    int s = 0;
#pragma unroll
    for (int i = 0; i < 10; ++i) {
        int idx = base + i;
        if (idx < N_NODES) s += deg[idx];
    }
    part[t] = s;
    __syncthreads();
    for (int d = 1; d < 1024; d <<= 1) {
        int v = (t >= d) ? part[t - d] : 0;
        __syncthreads();
        part[t] += v;
        __syncthreads();
    }
    int run = part[t] - s;
#pragma unroll
    for (int i = 0; i < 10; ++i) {
        int idx = base + i;
        if (idx < N_NODES) {
            off[idx] = run;
            cursor[idx] = run;
            run += deg[idx];
        }
    }
    if (t == 1023) off[N_NODES] = run;
}

__global__ __launch_bounds__(256) void slot_kernel(
    const int* __restrict__ edge_index, int* __restrict__ cursor,
    int* __restrict__ slot) {
    int e = blockIdx.x * 256 + threadIdx.x;
    if (e < N_EDGES) {
        int r = edge_index[N_EDGES + e];
        slot[e] = atomicAdd(&cursor[r], 1);
    }
}

// ---------------------------------------------------------------------------
// Edge kernel v4: R3 structure (full 8 tables, 64 KB LDS, 96 MFMA/tile, no
// duplicated work) + single-stage register prefetch pipeline at NATURAL
// register pressure (no launch_bounds min-waves — R4 lesson) + shfl epilogue
// (eaC/slC already in regs; saves ~20 VGPR vs per-lane row loads).
// Msg layout interleaved: Msg[slot*128 + col*4 + comp], shortx4 stores.
// ---------------------------------------------------------------------------
__global__ __launch_bounds__(256) void edge_kernel(
    const float* __restrict__ node_feats, const float* __restrict__ edge_attrs,
    const float* __restrict__ edge_feats, const int* __restrict__ edge_index,
    const unsigned short* __restrict__ Wc, const int* __restrict__ slot,
    unsigned short* __restrict__ Msg) {
    __shared__ short8 sW8[4096];  // 64 KB, B-fragment order
    {
        const short8* src = (const short8*)Wc;
        for (int i = threadIdx.x; i < 4096; i += 256) sW8[i] = src[i];
    }
    __syncthreads();

    const int lane = threadIdx.x & 63;
    const int m = lane & 15, q = lane >> 4;
    const int wave = (blockIdx.x * 256 + threadIdx.x) >> 6;
    const int stride = gridDim.x * 4;
    const int NT = N_EDGES / 16;

    int tile = wave;
    if (tile >= NT) return;

    float xsC[8], xvC[24], efC[8];
    f32x4 eaC;
    int slC;

    // prologue: load current tile's state
    {
        int e = tile * 16 + m;
        int snd = edge_index[e];
        const float* g = node_feats + snd * 128;
        *(f32x4*)&xsC[0] = *(const f32x4*)(g + q * 8);
        *(f32x4*)&xsC[4] = *(const f32x4*)(g + q * 8 + 4);
#pragma unroll
        for (int i = 0; i < 6; ++i)
            *(f32x4*)&xvC[i * 4] = *(const f32x4*)(g + 32 + q * 24 + i * 4);
        *(f32x4*)&efC[0] = *(const f32x4*)(edge_feats + e * 8);
        *(f32x4*)&efC[4] = *(const f32x4*)(edge_feats + e * 8 + 4);
        eaC = *(const f32x4*)(edge_attrs + e * 4);
        slC = slot[e];
    }

    while (tile < NT) {
        const int tn = tile + stride;
        const bool hasN = tn < NT;

        // ---- prefetch next tile's state (hidden behind current compute)
        float xsN[8], xvN[24], efN[8];
        f32x4 eaN;
        int slN;
        if (hasN) {
            int en = tn * 16 + m;
            int sndN = edge_index[en];
            const float* gN = node_feats + sndN * 128;
            *(f32x4*)&xsN[0] = *(const f32x4*)(gN + q * 8);
            *(f32x4*)&xsN[4] = *(const f32x4*)(gN + q * 8 + 4);
#pragma unroll
            for (int i = 0; i < 6; ++i)
                *(f32x4*)&xvN[i * 4] = *(const f32x4*)(gN + 32 + q * 24 + i * 4);
            *(f32x4*)&efN[0] = *(const f32x4*)(edge_feats + en * 8);
            *(f32x4*)&efN[4] = *(const f32x4*)(edge_feats + en * 8 + 4);
            eaN = *(const f32x4*)(edge_attrs + en * 4);
            slN = slot[en];
        }

        // ---- compute current tile
        float dt[8];
        {
            float y0 = eaC.y, y1 = eaC.z, y2 = eaC.w;
#pragma unroll
            for (int j = 0; j < 8; ++j)
                dt[j] = xvC[j * 3] * y0 + xvC[j * 3 + 1] * y1 + xvC[j * 3 + 2] * y2;
        }

        f32x4 z = {0.f, 0.f, 0.f, 0.f};
        f32x4 fA[2] = {z, z}, fB[2] = {z, z}, fD[2] = {z, z};
        f32x4 fC[3][2] = {{z, z}, {z, z}, {z, z}};

#pragma unroll
        for (int ks = 0; ks < 8; ++ks) {
            float h = efC[ks];
            float t[8];
            // xs vector -> tables A (0,1) and B (2,3)
#pragma unroll
            for (int j = 0; j < 8; ++j) t[j] = h * xsC[j];
            {
                short8 a = cvt8(t);
                fA[0] = __builtin_amdgcn_mfma_f32_16x16x32_bf16(a, sW8[(0 * 8 + ks) * 64 + lane], fA[0], 0, 0, 0);
                fA[1] = __builtin_amdgcn_mfma_f32_16x16x32_bf16(a, sW8[(1 * 8 + ks) * 64 + lane], fA[1], 0, 0, 0);
                fB[0] = __builtin_amdgcn_mfma_f32_16x16x32_bf16(a, sW8[(2 * 8 + ks) * 64 + lane], fB[0], 0, 0, 0);
                fB[1] = __builtin_amdgcn_mfma_f32_16x16x32_bf16(a, sW8[(3 * 8 + ks) * 64 + lane], fB[1], 0, 0, 0);
            }
            // xv components -> table C (4,5)
            {
                short8 bc0 = sW8[(4 * 8 + ks) * 64 + lane];
                short8 bc1 = sW8[(5 * 8 + ks) * 64 + lane];
#pragma unroll
                for (int c = 0; c < 3; ++c) {
#pragma unroll
                    for (int j = 0; j < 8; ++j) t[j] = h * xvC[j * 3 + c];
                    short8 a = cvt8(t);
                    fC[c][0] = __builtin_amdgcn_mfma_f32_16x16x32_bf16(a, bc0, fC[c][0], 0, 0, 0);
                    fC[c][1] = __builtin_amdgcn_mfma_f32_16x16x32_bf16(a, bc1, fC[c][1], 0, 0, 0);
                }
            }
            // dot vector -> table D (6,7)
            {
#pragma unroll
                for (int j = 0; j < 8; ++j) t[j] = h * dt[j];
                short8 a = cvt8(t);
                fD[0] = __builtin_amdgcn_mfma_f32_16x16x32_bf16(a, sW8[(6 * 8 + ks) * 64 + lane], fD[0], 0, 0, 0);
                fD[1] = __builtin_amdgcn_mfma_f32_16x16x32_bf16(a, sW8[(7 * 8 + ks) * 64 + lane], fD[1], 0, 0, 0);
            }
        }

        // ---- epilogue: shfl row-broadcast (lane m holds edge m's ea/slot)
#pragma unroll
        for (int t4 = 0; t4 < 4; ++t4) {
            int row = q * 4 + t4;
            float ysr = __shfl(eaC.x, row);
            float y0r = __shfl(eaC.y, row);
            float y1r = __shfl(eaC.z, row);
            float y2r = __shfl(eaC.w, row);
            int dr = __shfl(slC, row);
#pragma unroll
            for (int nt = 0; nt < 2; ++nt) {
                int col = nt * 16 + m;
                float pb = fB[nt][t4];
                shortx4 pk;
                pk[0] = bf16bits(ysr * fA[nt][t4] + fD[nt][t4]);
                pk[1] = bf16bits(y0r * pb + ysr * fC[0][nt][t4]);
                pk[2] = bf16bits(y1r * pb + ysr * fC[1][nt][t4]);
                pk[3] = bf16bits(y2r * pb + ysr * fC[2][nt][t4]);
                *(shortx4*)(Msg + (size_t)dr * 128 + col * 4) = pk;
            }
        }

        // ---- rotate pipeline
        tile = tn;
        if (hasN) {
#pragma unroll
            for (int j = 0; j < 8; ++j) { xsC[j] = xsN[j]; efC[j] = efN[j]; }
#pragma unroll
            for (int j = 0; j < 24; ++j) xvC[j] = xvN[j];
            eaC = eaN;
            slC = slN;
        }
    }
}

// ---------------------------------------------------------------------------
// Fused gather + node kernel (unchanged from R5; matches interleaved Msg).
// ---------------------------------------------------------------------------
__global__ __launch_bounds__(256) void node_kernel(
    const float* __restrict__ node_attrs, const unsigned short* __restrict__ Msg,
    const int* __restrict__ off, const unsigned short* __restrict__ WB0,
    const unsigned short* __restrict__ WB1, float* __restrict__ out) {
    __shared__ float sM[16][129];
    __shared__ float sAt[16][17];
    int n0 = blockIdx.x * 16;

    int nl = threadIdx.x >> 4;
    int cg = threadIdx.x & 15;
    int n = n0 + nl;
    int s0 = off[n], s1 = off[n + 1];
    float acc[8];
#pragma unroll
    for (int j = 0; j < 8; ++j) acc[j] = 0.f;
    for (int s = s0; s < s1; ++s) {
        f32x4 raw = *(const f32x4*)(Msg + (size_t)s * 128 + cg * 8);
        const unsigned short* us = (const unsigned short*)&raw;
#pragma unroll
        for (int j = 0; j < 8; ++j) acc[j] += bf2f(us[j]);
    }
#pragma unroll
    for (int j = 0; j < 8; ++j)
        sM[nl][(j & 3) * 32 + cg * 2 + (j >> 2)] = acc[j];
    sAt[nl][cg] = node_attrs[n * 16 + cg];
    __syncthreads();

    int p = threadIdx.x >> 6;
    int lane = threadIdx.x & 63;
    int m = lane & 15, q = lane >> 4;
    const unsigned short* WB = (p == 0) ? WB0 : WB1;
    int chb = p * 32;
    f32x4 z = {0.f, 0.f, 0.f, 0.f};
    f32x4 D0 = z, D1 = z;
#pragma unroll
    for (int ks = 0; ks < 16; ++ks) {
        int kb = ks * 32 + q * 8;
        float t[8];
#pragma unroll
        for (int j = 0; j < 8; ++j) {
            int k = kb + j;
            t[j] = sM[m][chb + (k >> 4)] * sAt[m][k & 15];
        }
        short8 a = cvt8(t);
        short8 b0 = *(const short8*)(WB + (ks * 64 + lane) * 8);
        short8 b1 = *(const short8*)(WB + ((16 + ks) * 64 + lane) * 8);
        D0 = __builtin_amdgcn_mfma_f32_16x16x32_bf16(a, b0, D0, 0, 0, 0);
        D1 = __builtin_amdgcn_mfma_f32_16x16x32_bf16(a, b1, D1, 0, 0, 0);
    }

#pragma unroll
    for (int t4 = 0; t4 < 4; ++t4) {
        int nl2 = q * 4 + t4;
        int nn = n0 + nl2;
        if (p == 0) {
            out[nn * 128 + m]      = sM[nl2][m] + D0[t4];
            out[nn * 128 + 16 + m] = sM[nl2][16 + m] + D1[t4];
        } else {
            int i = p - 1;
            out[nn * 128 + 32 + m * 3 + i]        = sM[nl2][chb + m] + D0[t4];
            out[nn * 128 + 32 + (16 + m) * 3 + i] = sM[nl2][chb + 16 + m] + D1[t4];
        }
    }
}

extern "C" void kernel_launch(void* const* d_in, const int* in_sizes, int n_in,
                              void* d_out, int out_size, void* d_ws, size_t ws_size,
                              hipStream_t stream) {
    (void)in_sizes; (void)n_in; (void)out_size; (void)ws_size;
    const float* node_attrs = (const float*)d_in[0];
    const float* node_feats = (const float*)d_in[1];
    const float* edge_attrs = (const float*)d_in[2];
    const float* edge_feats = (const float*)d_in[3];
    const int*   edge_index = (const int*)d_in[4];
    const float* Wgen = (const float*)d_in[5];
    const float* L1s  = (const float*)d_in[6];
    const float* L1v  = (const float*)d_in[7];
    const float* WS0  = (const float*)d_in[8];
    const float* WS1  = (const float*)d_in[9];
    const float* L2s  = (const float*)d_in[10];
    const float* L2v  = (const float*)d_in[11];
    float* out = (float*)d_out;
    char* ws = (char*)d_ws;

    unsigned short* Msg = (unsigned short*)ws;                 // 25,600,000
    unsigned short* Wc  = (unsigned short*)(ws + 25600000);    //     65,536
    unsigned short* WB0 = (unsigned short*)(ws + 25665536);    //     32,768
    unsigned short* WB1 = (unsigned short*)(ws + 25698304);    //     32,768
    int* deg    = (int*)(ws + 25731072);                       //     40,000
    int* off    = (int*)(ws + 25771072);                       //     40,004
    int* cursor = (int*)(ws + 25811080);                       //     40,000
    int* slot   = (int*)(ws + 25851080);                       //    400,000

    hipMemsetAsync(deg, 0, 40000, stream);
    prep_kernel<<<647, 256, 0, stream>>>(Wgen, L1s, L1v, WS0, WS1, L2s, L2v,
                                         edge_index, Wc, WB0, WB1, deg);
    scan_kernel<<<1, 1024, 0, stream>>>(deg, off, cursor);
    slot_kernel<<<391, 256, 0, stream>>>(edge_index, cursor, slot);
    edge_kernel<<<512, 256, 0, stream>>>(node_feats, edge_attrs, edge_feats,
                                         edge_index, Wc, slot, Msg);
    node_kernel<<<625, 256, 0, stream>>>(node_attrs, Msg, off, WB0, WB1, out);
}